// Round 5
// baseline (30134.366 us; speedup 1.0000x reference)
//
#include <hip/hip_runtime.h>
#include <cstdio>

#define NBLK 256
#define NTHR 256

typedef unsigned char uchar;
typedef unsigned long long u64;
typedef short bf16x8 __attribute__((ext_vector_type(8)));
typedef float f32x4  __attribute__((ext_vector_type(4)));

// ---------------- ws layout (bytes) ----------------
static constexpr size_t OFF_W0E = 0;                               // 2048x544 bf16 (enc L0: [x(32)|h0(512)])
static constexpr size_t OFF_W1E = OFF_W0E + 2048ull*544*2;         // 2048x1024 bf16 (enc L1: [h0|h1])
static constexpr size_t OFF_W0D = OFF_W1E + 2048ull*1024*2;        // 2048x1056 bf16 (dec L0: [ctx|dec_in|pad|h0|pad])
static constexpr size_t OFF_W1D = OFF_W0D + 2048ull*1056*2;        // 2048x1024 bf16 (dec L1)
static constexpr size_t OFF_WDP = OFF_W1D + 2048ull*1024*2;        // 640x512 bf16 (W_dec + fc_W row 512)
static constexpr size_t OFF_WEP = OFF_WDP + 640ull*512*2;          // 512x512 bf16 (W_enc)
static constexpr size_t OFF_BE0 = OFF_WEP + 512ull*512*2;          // 2048 f32 interleaved biases
static constexpr size_t OFF_BE1 = OFF_BE0 + 2048*4;
static constexpr size_t OFF_BD0 = OFF_BE1 + 2048*4;
static constexpr size_t OFF_BD1 = OFF_BD0 + 2048*4;
static constexpr size_t OFF_XBF = OFF_BD1 + 2048*4;                // [t][b][32] bf16 src transposed
static constexpr size_t OFF_H0E = OFF_XBF + 512ull*256*32*2;       // 2 x [b][512] bf16 (double buffered)
static constexpr size_t OFF_H1E = OFF_H0E + 2ull*256*512*2;
static constexpr size_t OFF_XD0 = OFF_H1E + 2ull*256*512*2;        // 2 x [b][1056] bf16 decoder L0 input
static constexpr size_t OFF_XD1 = OFF_XD0 + 2ull*256*1056*2;       // 2 x [b][1024] bf16 decoder L1 input [h0|h1]
static constexpr size_t OFF_DP  = OFF_XD1 + 2ull*256*1024*2;       // [b][520] f32 (dp 0..511, raw pred at 512)
static constexpr size_t OFF_C0  = OFF_DP  + 256ull*520*4;          // [b][512] f32 (atomically accumulated)
static constexpr size_t OFF_BAR = OFF_C0  + 256ull*512*4;          // hierarchical barrier (8 KiB)
static constexpr size_t BAR_SZ  = 8192;
static constexpr size_t OFF_ENCF8 = OFF_BAR + BAR_SZ;              // [b][t][h] fp8 (x16 scale)
static constexpr size_t OFF_A1T   = OFF_ENCF8 + 256ull*512*512;    // [b][kq(128)][s(512)] dword of 4 fp8 (x16)
static constexpr size_t WS_NEED   = OFF_A1T + 256ull*128*512*4;    // ~163 MiB

struct KArgs {
  const float* in[22];
  float* out;
  uchar* ws;
};

__device__ __forceinline__ float fexp2(float x){ return __builtin_amdgcn_exp2f(x); }
__device__ __forceinline__ float frcp (float x){ return __builtin_amdgcn_rcpf(x); }
__device__ __forceinline__ float sigm (float x){ return frcp(1.f + fexp2(x * -1.44269504f)); }
__device__ __forceinline__ float tanh_(float x){ return 2.f*frcp(1.f + fexp2(x * -2.88539008f)) - 1.f; }
__device__ __forceinline__ unsigned short f2bf(float f){
  unsigned u = __float_as_uint(f);
  return (unsigned short)((u + 0x7fffu + ((u>>16)&1u)) >> 16);
}
__device__ __forceinline__ bf16x8 ldfrag(const uchar* p){ return *(const bf16x8*)p; }

// ---- coherent (LLC-level) ops for cross-XCD state; weights stay plain/cached.
__device__ __forceinline__ u64 ld_c64(const void* p){
  return __hip_atomic_load((const u64*)p, __ATOMIC_RELAXED, __HIP_MEMORY_SCOPE_AGENT);
}
__device__ __forceinline__ unsigned ld_c32(const void* p){
  return __hip_atomic_load((const unsigned*)p, __ATOMIC_RELAXED, __HIP_MEMORY_SCOPE_AGENT);
}
__device__ __forceinline__ float ld_c32f(const void* p){ return __uint_as_float(ld_c32(p)); }
__device__ __forceinline__ void st_c64(void* p, u64 v){
  __hip_atomic_store((u64*)p, v, __ATOMIC_RELAXED, __HIP_MEMORY_SCOPE_AGENT);
}
__device__ __forceinline__ void st_c32(void* p, unsigned v){
  __hip_atomic_store((unsigned*)p, v, __ATOMIC_RELAXED, __HIP_MEMORY_SCOPE_AGENT);
}
__device__ __forceinline__ bf16x8 ldfrag_c(const uchar* p){
  union { bf16x8 v; u64 u[2]; } r;
  r.u[0] = ld_c64(p); r.u[1] = ld_c64(p + 8);
  return r.v;
}

// Hierarchical grid barrier: 32 group counters (8 arrivals each) -> master (32) -> flag.
// full=true adds agent fences (wbl2/inv) — used ONCE after setup.
__device__ __forceinline__ void gbar(uchar* bar, unsigned target, bool full) {
  __builtin_amdgcn_s_waitcnt(0);
  __syncthreads();
  if (threadIdx.x == 0) {
    if (full) __builtin_amdgcn_fence(__ATOMIC_RELEASE, "agent");
    unsigned g = blockIdx.x & 31;
    unsigned* cnt    = (unsigned*)(bar + g*128);
    unsigned* master = (unsigned*)(bar + 32*128);
    unsigned* flag   = (unsigned*)(bar + 33*128);
    bool setter = false;
    unsigned prev = __hip_atomic_fetch_add(cnt, 1u, __ATOMIC_RELAXED, __HIP_MEMORY_SCOPE_AGENT);
    if (prev == 8u*target - 1u) {
      unsigned pm = __hip_atomic_fetch_add(master, 1u, __ATOMIC_RELAXED, __HIP_MEMORY_SCOPE_AGENT);
      if (pm == 32u*target - 1u) {
        __hip_atomic_store(flag, target, __ATOMIC_RELAXED, __HIP_MEMORY_SCOPE_AGENT);
        setter = true;
      }
    }
    if (!setter) {
      while (__hip_atomic_load(flag, __ATOMIC_RELAXED, __HIP_MEMORY_SCOPE_AGENT) < target) {
        __builtin_amdgcn_s_sleep(8);
      }
    }
    if (full) __builtin_amdgcn_fence(__ATOMIC_ACQUIRE, "agent");
  }
  __syncthreads();
}

__global__ void __launch_bounds__(NTHR, 1) seq2seq(KArgs A) {
  const int bid = blockIdx.x, tid = threadIdx.x;
  const int lane = tid & 63, wv = tid >> 6;
  const int q = lane >> 4, cl = lane & 15;
  uchar* ws = A.ws;

  const float* src = A.in[0];
  const float* ew0 = A.in[1]; const float* eu0 = A.in[2];
  const float* ebi0= A.in[3]; const float* ebh0= A.in[4];
  const float* ew1 = A.in[5]; const float* eu1 = A.in[6];
  const float* ebi1= A.in[7]; const float* ebh1= A.in[8];
  const float* dw0 = A.in[9]; const float* du0 = A.in[10];
  const float* dbi0= A.in[11]; const float* dbh0= A.in[12];
  const float* dw1 = A.in[13]; const float* du1 = A.in[14];
  const float* dbi1= A.in[15]; const float* dbh1= A.in[16];
  const float* attW= A.in[17]; const float* attB= A.in[18];
  const float* vW  = A.in[19]; const float* fcW = A.in[20];
  const float* fcB = A.in[21];

  uchar* W0E = ws + OFF_W0E; uchar* W1E = ws + OFF_W1E;
  uchar* W0D = ws + OFF_W0D; uchar* W1D = ws + OFF_W1D;
  uchar* WDP = ws + OFF_WDP; uchar* WEP = ws + OFF_WEP;
  float* BE0 = (float*)(ws + OFF_BE0); float* BE1 = (float*)(ws + OFF_BE1);
  float* BD0 = (float*)(ws + OFF_BD0); float* BD1 = (float*)(ws + OFF_BD1);
  uchar* XBF = ws + OFF_XBF;
  uchar* H0E[2] = { ws + OFF_H0E, ws + OFF_H0E + 256*512*2 };
  uchar* H1E[2] = { ws + OFF_H1E, ws + OFF_H1E + 256*512*2 };
  uchar* XD0[2] = { ws + OFF_XD0, ws + OFF_XD0 + 256*1056*2 };
  uchar* XD1[2] = { ws + OFF_XD1, ws + OFF_XD1 + 256*1024*2 };
  float* DP  = (float*)(ws + OFF_DP);
  float* C0g = (float*)(ws + OFF_C0);
  uchar* BAR = ws + OFF_BAR;
  uchar* ENCF8 = ws + OFF_ENCF8;
  unsigned* A1T = (unsigned*)(ws + OFF_A1T);

  __shared__ float smh[64][65];
  __shared__ float sm_d[512];
  __shared__ float sm_w[512];
  __shared__ float sm_ctx[512];
  __shared__ float sm_r[8];
  __shared__ float sm_c0[4][64];

  unsigned ep = 0;
  const int T = NBLK*NTHR; const int gt = bid*NTHR + tid;

  // =================== SETUP (plain cached writes; flushed by the one full barrier) ===================
  {
    for (int i = gt; i < 2048*544; i += T) {
      int np = i / 544, k = i - np*544;
      int r = (np & 3)*512 + (np >> 2);
      float v = (k < 32) ? ew0[r*32 + k] : eu0[r*512 + (k-32)];
      ((unsigned short*)W0E)[i] = f2bf(v);
    }
    for (int i = gt; i < 2048*1024; i += T) {
      int np = i >> 10, k = i & 1023;
      int r = (np & 3)*512 + (np >> 2);
      float v = (k < 512) ? ew1[r*512 + k] : eu1[r*512 + (k-512)];
      ((unsigned short*)W1E)[i] = f2bf(v);
    }
    for (int i = gt; i < 2048*1056; i += T) {
      int np = i / 1056, k = i - np*1056;
      int r = (np & 3)*512 + (np >> 2);
      float v;
      if (k < 512) v = dw0[r*513 + 1 + k];            // context weights
      else if (k == 512) v = dw0[r*513];              // dec_in weight
      else if (k >= 520 && k < 1032) v = du0[r*512 + (k-520)];
      else v = 0.f;
      ((unsigned short*)W0D)[i] = f2bf(v);
    }
    for (int i = gt; i < 2048*1024; i += T) {
      int np = i >> 10, k = i & 1023;
      int r = (np & 3)*512 + (np >> 2);
      float v = (k < 512) ? dw1[r*512 + k] : du1[r*512 + (k-512)];
      ((unsigned short*)W1D)[i] = f2bf(v);
    }
    for (int i = gt; i < 640*512; i += T) {
      int j = i >> 9, k = i & 511;
      float v = (j < 512) ? attW[j*1024 + 512 + k] : ((j == 512) ? fcW[k] : 0.f);
      ((unsigned short*)WDP)[i] = f2bf(v);
    }
    for (int i = gt; i < 512*512; i += T) {
      int j = i >> 9, k = i & 511;
      ((unsigned short*)WEP)[i] = f2bf(attW[j*1024 + k]);
    }
    for (int i = gt; i < 2048; i += T) {
      int r = (i & 3)*512 + (i >> 2);
      BE0[i] = ebi0[r] + ebh0[r];
      BE1[i] = ebi1[r] + ebh1[r];
      BD0[i] = dbi0[r] + dbh0[r];
      BD1[i] = dbi1[r] + dbh1[r];
    }
    for (int i = gt; i < 512*256*32; i += T) {
      int t = i >> 13, rem = i & 8191;
      int b = rem >> 5, d = rem & 31;
      ((unsigned short*)XBF)[i] = f2bf(src[(b*512 + t)*32 + d]);
    }
    // zero H0E,H1E,XD0,XD1 (contiguous region) + C0g
    unsigned* Z = (unsigned*)(ws + OFF_H0E);
    for (int i = gt; i < 794624; i += T) Z[i] = 0u;
    for (int i = gt; i < 256*512; i += T) C0g[i] = 0.f;
  }
  gbar(BAR, ++ep, true);   // the ONE full-fence barrier

  float cst[16];
#pragma unroll
  for (int i = 0; i < 16; ++i) cst[i] = 0.f;

  // GEMM(gates^T, 256 rows x 64 cols, 4 waves stacked on M) + fused LSTM cell
  // A-frags (weights): plain cached loads (XCD-L2-resident). B-frags (states): coherent loads.
  auto run_gemm_cell = [&](const uchar* W, int Kp2, int nkc, auto bfn,
                           const float* bias, int rowb_blk, int bb,
                           uchar* d1, int s1, uchar* d2, int s2, uchar* f8, int s8) {
    f32x4 acc[16];
#pragma unroll
    for (int i = 0; i < 16; ++i) acc[i] = (f32x4){0.f,0.f,0.f,0.f};
    const int rowb_wave = rowb_blk + wv*64;
#pragma unroll 2
    for (int kc = 0; kc < nkc; ++kc) {
      bf16x8 bfr[4], afr[4];
#pragma unroll
      for (int ni = 0; ni < 4; ++ni) bfr[ni] = ldfrag_c(bfn(kc, bb + ni*16 + cl));
#pragma unroll
      for (int mi = 0; mi < 4; ++mi)
        afr[mi] = ldfrag(W + (size_t)(rowb_wave + mi*16 + cl)*Kp2 + (size_t)kc*64 + q*16);
#pragma unroll
      for (int mi = 0; mi < 4; ++mi)
#pragma unroll
        for (int ni = 0; ni < 4; ++ni)
          acc[mi*4+ni] = __builtin_amdgcn_mfma_f32_16x16x32_bf16(afr[mi], bfr[ni], acc[mi*4+ni], 0,0,0);
    }
    // cell: lane holds 4 gates (regs) for one (j,b) per tile
#pragma unroll
    for (int mi = 0; mi < 4; ++mi) {
      int row = rowb_wave + mi*16 + 4*q;
      f32x4 bb4 = *(const f32x4*)(bias + row);
#pragma unroll
      for (int ni = 0; ni < 4; ++ni) {
        f32x4 g = acc[mi*4+ni];
        float ii = sigm(g[0] + bb4[0]);
        float ff = sigm(g[1] + bb4[1]);
        float gg = tanh_(g[2] + bb4[2]);
        float oo = sigm(g[3] + bb4[3]);
        float cc = ff*cst[mi*4+ni] + ii*gg;
        cst[mi*4+ni] = cc;
        smh[ni*16 + cl][wv*16 + mi*4 + q] = oo * tanh_(cc);
      }
    }
    __syncthreads();
    // coalesced write-out (coherent stores: cross-XCD visible at LLC, no dirty L2 lines)
    {
      int b = tid & 63, jq = tid >> 6;
      int jb = (rowb_blk >> 2) + jq*16;
      float v[16];
#pragma unroll
      for (int u = 0; u < 16; ++u) v[u] = smh[b][jq*16 + u];
      unsigned pk[8];
#pragma unroll
      for (int u = 0; u < 8; ++u) pk[u] = (unsigned)f2bf(v[2*u]) | ((unsigned)f2bf(v[2*u+1]) << 16);
      u64 q0 = (u64)pk[0] | ((u64)pk[1] << 32);
      u64 q1 = (u64)pk[2] | ((u64)pk[3] << 32);
      u64 q2 = (u64)pk[4] | ((u64)pk[5] << 32);
      u64 q3 = (u64)pk[6] | ((u64)pk[7] << 32);
      uchar* p1 = d1 + ((size_t)(bb+b)*s1 + jb)*2;
      st_c64(p1,      q0); st_c64(p1 + 8,  q1);
      st_c64(p1 + 16, q2); st_c64(p1 + 24, q3);
      if (d2) {
        uchar* p2 = d2 + ((size_t)(bb+b)*s2 + jb)*2;
        st_c64(p2,      q0); st_c64(p2 + 8,  q1);
        st_c64(p2 + 16, q2); st_c64(p2 + 24, q3);
      }
      if (f8) {
        unsigned f[4];
#pragma unroll
        for (int u = 0; u < 4; ++u) {
          unsigned r = __builtin_amdgcn_cvt_pk_fp8_f32(v[4*u]*16.f,   v[4*u+1]*16.f, 0, false);
          r          = __builtin_amdgcn_cvt_pk_fp8_f32(v[4*u+2]*16.f, v[4*u+3]*16.f, r, true);
          f[u] = r;
        }
        uchar* p8 = f8 + (size_t)(bb+b)*s8 + jb;
        st_c64(p8,     (u64)f[0] | ((u64)f[1] << 32));
        st_c64(p8 + 8, (u64)f[2] | ((u64)f[3] << 32));
      }
    }
    __syncthreads();
  };

  // =================== ENCODER: 514 pipelined phases ===================
  // XCD-aligned: weight-slice id m = bid & 7 (round-robin block->XCD dispatch),
  // so all 4 n-blocks of a slice share one XCD's L2 -> ~0.92 MB weights/XCD resident.
  for (int p = 0; p <= 513; ++p) {
    if (bid < 32 && p < 512) {
      const int m = bid & 7, n = bid >> 3;
      const uchar* xrow = XBF + (size_t)p*256*64;
      const uchar* h0rd = H0E[(p+1)&1];   // h0(p-1)
      auto bfn = [&](int kc, int brow)->const uchar* {
        if (kc == 0) return xrow + (size_t)brow*64 + q*16;
        return h0rd + (size_t)brow*1024 + (size_t)(kc-1)*64 + q*16;
      };
      run_gemm_cell(W0E, 544*2, 17, bfn, BE0, m*256, n*64,
                    H0E[p&1], 512, nullptr, 0, nullptr, 0);
    } else if (bid >= 32 && bid < 64 && p >= 1 && p <= 512) {
      const int m = bid & 7, n = (bid-32) >> 3;
      const int t = p - 1;
      const uchar* h0rd = H0E[(p+1)&1];   // h0(p-1) == h0(t)
      const uchar* h1rd = H1E[(p+1)&1];   // h1(p-2) == h1(t-1)
      auto bfn = [&](int kc, int brow)->const uchar* {
        const uchar* base = (kc < 16) ? h0rd : h1rd;
        int k0 = (kc < 16) ? kc : kc - 16;
        return base + (size_t)brow*1024 + (size_t)k0*64 + q*16;
      };
      run_gemm_cell(W1E, 1024*2, 32, bfn, BE1, m*256, n*64,
                    H1E[p&1], 512,
                    nullptr, 0,
                    ENCF8 + (size_t)t*512, 512*512);
    } else if (bid >= 64 && bid < 96 && p >= 2) {
      // PROJ: E = W_enc @ h1(t) + attB ; emit C0 partials + A1 fp8
      const int t = p - 2;
      const int m = bid & 7, n = (bid-64) >> 3;
      const uchar* h1rd = H1E[(p+1)&1];              // h1(p-2) == h1(t)
      const int rb = m*64 + wv*16;
      f32x4 acc[4];
#pragma unroll
      for (int i = 0; i < 4; ++i) acc[i] = (f32x4){0.f,0.f,0.f,0.f};
#pragma unroll 2
      for (int kc = 0; kc < 16; ++kc) {
        bf16x8 afr = ldfrag(WEP + (size_t)(rb + cl)*1024 + (size_t)kc*64 + q*16);
        bf16x8 bfr[4];
#pragma unroll
        for (int ni = 0; ni < 4; ++ni)
          bfr[ni] = ldfrag_c(h1rd + (size_t)(n*64 + ni*16 + cl)*1024 + (size_t)kc*64 + q*16);
#pragma unroll
        for (int ni = 0; ni < 4; ++ni)
          acc[ni] = __builtin_amdgcn_mfma_f32_16x16x32_bf16(afr, bfr[ni], acc[ni], 0,0,0);
      }
      const int k0 = rb + 4*q;
      f32x4 ab = *(const f32x4*)(attB + k0);
      f32x4 vv = *(const f32x4*)(vW + k0);
      const int kq = k0 >> 2;
      float part[4];
#pragma unroll
      for (int ni = 0; ni < 4; ++ni) {
        f32x4 e = acc[ni];
        float t0 = tanh_(e[0] + ab[0]);
        float t1 = tanh_(e[1] + ab[1]);
        float t2 = tanh_(e[2] + ab[2]);
        float t3 = tanh_(e[3] + ab[3]);
        part[ni] = vv[0]*t0 + vv[1]*t1 + vv[2]*t2 + vv[3]*t3;
        float a0 = vv[0]*(1.f-t0*t0)*16.f, a1 = vv[1]*(1.f-t1*t1)*16.f;
        float a2 = vv[2]*(1.f-t2*t2)*16.f, a3 = vv[3]*(1.f-t3*t3)*16.f;
        unsigned u = __builtin_amdgcn_cvt_pk_fp8_f32(a0, a1, 0, false);
        u          = __builtin_amdgcn_cvt_pk_fp8_f32(a2, a3, u, true);
        int b = n*64 + ni*16 + cl;
        st_c32(&A1T[((size_t)b*128 + kq)*512 + t], u);
      }
#pragma unroll
      for (int ni = 0; ni < 4; ++ni) {
        float v = part[ni];
        v += __shfl_xor(v, 16);
        v += __shfl_xor(v, 32);
        if (lane < 16) sm_c0[wv][ni*16 + lane] = v;
      }
      __syncthreads();
      if (tid < 64)
        atomicAdd(&C0g[(size_t)(n*64 + tid)*512 + t],
                  sm_c0[0][tid] + sm_c0[1][tid] + sm_c0[2][tid] + sm_c0[3][tid]);
      __syncthreads();
    }
    gbar(BAR, ++ep, false);
  }

  // =================== TRANSITION ===================
  {
    uchar* x0 = XD0[0];
    uchar* x1 = XD1[0];
    const unsigned* h0f = (const unsigned*)H0E[1];  // h0(511)
    const unsigned* h1f = (const unsigned*)H1E[0];  // h1(511)
    for (int i = gt; i < 65536; i += T) {           // u32 units (2 bf16 each)
      int b = i >> 8, j = i & 255;
      unsigned v0 = ld_c32(h0f + i);
      unsigned v1 = ld_c32(h1f + i);
      st_c32(x0 + (size_t)b*2112 + 1040 + j*4, v0); // cols 520.. (h0)
      st_c32(x1 + (size_t)b*2048 + 1024 + j*4, v1); // cols 512.. (h1)
    }
    for (int i = gt; i < 256; i += T) {
      unsigned v = (unsigned)f2bf(src[(i*512 + 511)*32 + 31]);  // dec_in0 (col 513 = pad = 0)
      st_c32(x0 + (size_t)i*2112 + 1024, v);
    }
  }
  gbar(BAR, ++ep, false);

  // =================== DECODER ===================
  for (int t = 0; t <= 24; ++t) {
    // ---- P3b: dp = [W_dec; fc_W] @ h1(t-1) ----
    if (bid < 20) {
      const int m = bid >> 2, n = bid & 3;
      const uchar* xb = XD1[t&1];
      f32x4 acc[8];
#pragma unroll
      for (int i = 0; i < 8; ++i) acc[i] = (f32x4){0.f,0.f,0.f,0.f};
      const int rb = m*128 + wv*32;
#pragma unroll 2
      for (int kc = 0; kc < 16; ++kc) {
        bf16x8 bfr[4], afr[2];
#pragma unroll
        for (int ni = 0; ni < 4; ++ni)
          bfr[ni] = ldfrag_c(xb + (size_t)(n*64 + ni*16 + cl)*2048 + 1024 + (size_t)kc*64 + q*16);
#pragma unroll
        for (int mi = 0; mi < 2; ++mi)
          afr[mi] = ldfrag(WDP + (size_t)(rb + mi*16 + cl)*1024 + (size_t)kc*64 + q*16);
#pragma unroll
        for (int mi = 0; mi < 2; ++mi)
#pragma unroll
          for (int ni = 0; ni < 4; ++ni)
            acc[mi*4+ni] = __builtin_amdgcn_mfma_f32_16x16x32_bf16(afr[mi], bfr[ni], acc[mi*4+ni], 0,0,0);
      }
#pragma unroll
      for (int mi = 0; mi < 2; ++mi) {
        int j0 = rb + mi*16 + 4*q;
        if (j0 < 520) {
#pragma unroll
          for (int ni = 0; ni < 4; ++ni) {
            int bcol = n*64 + ni*16 + cl;
            union { f32x4 v; u64 u[2]; } cv; cv.v = acc[mi*4+ni];
            float* dst = DP + (size_t)bcol*520 + j0;
            st_c64(dst,     cv.u[0]);
            st_c64(dst + 2, cv.u[1]);
          }
        }
      }
    }
    gbar(BAR, ++ep, false);

    // ---- P1: pred/dec_in + scores(Taylor) + softmax + context (block b = bid) ----
    {
      const int b = bid;
      float* dpb = DP + (size_t)b*520;
      uchar* xd0c = XD0[t&1];
      if (tid == 0 && t >= 1) {
        float pred = ld_c32f(dpb + 512) + fcB[0];
        A.out[b*24 + (t-1)] = pred;
        if (t < 24) {
          float hist = src[(b*512 + 511)*32 + 17];
          float dec_in = 0.8f*pred + 0.2f*hist;
          st_c32(xd0c + (size_t)b*2112 + 1024, (unsigned)f2bf(dec_in));
        }
      }
      if (t < 24) {
        sm_d[tid]       = ld_c32f(dpb + tid)       * 0.0625f;
        sm_d[tid + 256] = ld_c32f(dpb + tid + 256) * 0.0625f;
        __syncthreads();
        const unsigned* a1 = A1T + (size_t)b*128*512;
        float s0 = ld_c32f(C0g + (size_t)b*512 + tid);
        float s1 = ld_c32f(C0g + (size_t)b*512 + tid + 256);
        for (int kq = 0; kq < 128; ++kq) {
          unsigned u0 = ld_c32(a1 + kq*512 + tid);
          unsigned u1 = ld_c32(a1 + kq*512 + tid + 256);
          float d0 = sm_d[kq*4 + 0];
          float d1 = sm_d[kq*4 + 1];
          float d2 = sm_d[kq*4 + 2];
          float d3 = sm_d[kq*4 + 3];
          s0 += __builtin_amdgcn_cvt_f32_fp8(u0, 0) * d0
              + __builtin_amdgcn_cvt_f32_fp8(u0, 1) * d1
              + __builtin_amdgcn_cvt_f32_fp8(u0, 2) * d2
              + __builtin_amdgcn_cvt_f32_fp8(u0, 3) * d3;
          s1 += __builtin_amdgcn_cvt_f32_fp8(u1, 0) * d0
              + __builtin_amdgcn_cvt_f32_fp8(u1, 1) * d1
              + __builtin_amdgcn_cvt_f32_fp8(u1, 2) * d2
              + __builtin_amdgcn_cvt_f32_fp8(u1, 3) * d3;
        }
        // softmax over 512
        float mx = fmaxf(s0, s1);
#pragma unroll
        for (int o = 1; o < 64; o <<= 1) mx = fmaxf(mx, __shfl_xor(mx, o));
        if (lane == 0) sm_r[wv] = mx;
        __syncthreads();
        mx = fmaxf(fmaxf(sm_r[0], sm_r[1]), fmaxf(sm_r[2], sm_r[3]));
        float e0 = fexp2((s0 - mx)*1.44269504f);
        float e1 = fexp2((s1 - mx)*1.44269504f);
        float sum = e0 + e1;
#pragma unroll
        for (int o = 1; o < 64; o <<= 1) sum += __shfl_xor(sum, o);
        if (lane == 0) sm_r[4 + wv] = sum;
        __syncthreads();
        sum = sm_r[4] + sm_r[5] + sm_r[6] + sm_r[7];
        float inv = frcp(sum) * 0.0625f;   // fold fp8 x16 scale of enc_outs
        sm_w[tid] = e0*inv; sm_w[tid + 256] = e1*inv;
        sm_ctx[tid] = 0.f;  sm_ctx[tid + 256] = 0.f;
        __syncthreads();
        // context = sum_s w_s * enc_outs[b,s,:]
        {
          int hp = (tid & 127)*4, sh = tid >> 7;
          const uchar* e8 = ENCF8 + (size_t)b*262144 + hp;
          float a0=0.f, a1f=0.f, a2=0.f, a3=0.f;
          for (int i = 0; i < 256; ++i) {
            int s = sh*256 + i;
            unsigned u = ld_c32(e8 + (size_t)s*512);
            float w = sm_w[s];
            a0  += w*__builtin_amdgcn_cvt_f32_fp8(u, 0);
            a1f += w*__builtin_amdgcn_cvt_f32_fp8(u, 1);
            a2  += w*__builtin_amdgcn_cvt_f32_fp8(u, 2);
            a3  += w*__builtin_amdgcn_cvt_f32_fp8(u, 3);
          }
          atomicAdd(&sm_ctx[hp+0], a0);
          atomicAdd(&sm_ctx[hp+1], a1f);
          atomicAdd(&sm_ctx[hp+2], a2);
          atomicAdd(&sm_ctx[hp+3], a3);
        }
        __syncthreads();
        unsigned pk0 = (unsigned)f2bf(sm_ctx[2*tid]) | ((unsigned)f2bf(sm_ctx[2*tid+1]) << 16);
        st_c32(xd0c + (size_t)b*2112 + tid*4, pk0);
      }
    }
    gbar(BAR, ++ep, false);

    // ---- P2: decoder L0 ----
    if (t < 24 && bid < 32) {
      const int m = bid & 7, n = bid >> 3;
      const uchar* xb = XD0[t&1];
      auto bfn = [&](int kc, int brow)->const uchar* {
        return xb + (size_t)brow*2112 + (size_t)kc*64 + q*16;
      };
      run_gemm_cell(W0D, 1056*2, 33, bfn, BD0, m*256, n*64,
                    XD1[t&1], 1024,
                    XD0[(t+1)&1] + 520*2, 1056,
                    nullptr, 0);
    }
    gbar(BAR, ++ep, false);

    // ---- P3: decoder L1 ----
    if (t < 24 && bid >= 32 && bid < 64) {
      const int m = bid & 7, n = (bid-32) >> 3;
      const uchar* xb = XD1[t&1];
      auto bfn = [&](int kc, int brow)->const uchar* {
        return xb + (size_t)brow*2048 + (size_t)kc*64 + q*16;
      };
      run_gemm_cell(W1D, 1024*2, 32, bfn, BD1, m*256, n*64,
                    XD1[(t+1)&1] + 512*2, 1024,
                    nullptr, 0, nullptr, 0);
    }
    gbar(BAR, ++ep, false);
  }
}

extern "C" void kernel_launch(void* const* d_in, const int* in_sizes, int n_in,
                              void* d_out, int out_size, void* d_ws, size_t ws_size,
                              hipStream_t stream) {
  (void)in_sizes; (void)n_in; (void)out_size;
  if (ws_size < WS_NEED) {
    fprintf(stderr, "seq2seq: ws too small: have %zu need %zu — NOT launching\n",
            ws_size, (size_t)WS_NEED);
    return;
  }
  // zero barrier region every launch (ws is re-poisoned between replays)
  (void)hipMemsetAsync((char*)d_ws + OFF_BAR, 0, BAR_SZ, stream);
  KArgs a;
  for (int i = 0; i < 22; ++i) a.in[i] = (const float*)d_in[i];
  a.out = (float*)d_out;
  a.ws  = (uchar*)d_ws;
  void* args[] = { (void*)&a };
  hipError_t e = hipLaunchCooperativeKernel((const void*)seq2seq, dim3(NBLK), dim3(NTHR),
                                            args, 0, stream);
  if (e != hipSuccess) {
    fprintf(stderr, "seq2seq: coop launch failed (%d: %s), falling back to plain launch\n",
            (int)e, hipGetErrorString(e));
    seq2seq<<<dim3(NBLK), dim3(NTHR), 0, stream>>>(a);
  }
}

// Round 6
// 10002.973 us; speedup vs baseline: 3.0125x; 3.0125x over previous
//
#include <hip/hip_runtime.h>
#include <cstdio>

#define NBLK 256
#define NTHR 256

typedef unsigned char uchar;
typedef unsigned long long u64;
typedef short bf16x8 __attribute__((ext_vector_type(8)));
typedef float f32x4  __attribute__((ext_vector_type(4)));

// ---------------- ws layout (bytes) ----------------
static constexpr size_t OFF_WX  = 0;                              // 2048x32 bf16 (enc L0 x-weights)
static constexpr size_t OFF_W0H = OFF_WX  + 2048ull*32*2;         // 2048x512 bf16 (enc L0 h-weights)
static constexpr size_t OFF_W1E = OFF_W0H + 2048ull*512*2;        // 2048x1024 bf16 (enc L1 [h0|h1])
static constexpr size_t OFF_W0D = OFF_W1E + 2048ull*1024*2;       // 2048x1056 bf16 (dec L0)
static constexpr size_t OFF_W1D = OFF_W0D + 2048ull*1056*2;       // 2048x1024 bf16 (dec L1)
static constexpr size_t OFF_WDP = OFF_W1D + 2048ull*1024*2;       // 640x512 bf16 (W_dec + fc_W row 512)
static constexpr size_t OFF_WEP = OFF_WDP + 640ull*512*2;         // 512x512 bf16 (W_enc)
static constexpr size_t OFF_BE0 = OFF_WEP + 512ull*512*2;         // 2048 f32 biases (interleaved rows)
static constexpr size_t OFF_BE1 = OFF_BE0 + 2048*4;
static constexpr size_t OFF_BD0 = OFF_BE1 + 2048*4;
static constexpr size_t OFF_BD1 = OFF_BD0 + 2048*4;
static constexpr size_t OFF_XBF = OFF_BD1 + 2048*4;               // [t][b][32] bf16
static constexpr size_t OFF_H0E = OFF_XBF + 512ull*256*32*2;      // 2 x [b][512] bf16
static constexpr size_t OFF_H1E = OFF_H0E + 2ull*256*512*2;
static constexpr size_t OFF_XD0 = OFF_H1E + 2ull*256*512*2;       // 2 x [b][1056] bf16
static constexpr size_t OFF_XD1 = OFF_XD0 + 2ull*256*1056*2;      // 2 x [b][1024] bf16
static constexpr size_t OFF_DP  = OFF_XD1 + 2ull*256*1024*2;      // [b][520] f32
static constexpr size_t OFF_C0  = OFF_DP  + 256ull*520*4;         // [b][512] f32
static constexpr size_t OFF_CS0 = OFF_C0  + 256ull*512*4;         // [b][512] f32 final c0
static constexpr size_t OFF_CS1 = OFF_CS0 + 256ull*512*4;         // [b][512] f32 final c1
static constexpr size_t OFF_BAR = OFF_CS1 + 256ull*512*4;         // barrier (8 KiB)
static constexpr size_t BAR_SZ  = 8192;
static constexpr size_t OFF_ENCF8 = OFF_BAR + BAR_SZ;             // [b][t][h] fp8 (x16)
static constexpr size_t OFF_A1T   = OFF_ENCF8 + 256ull*512*512;   // [b][kq][s] u32 of 4 fp8 (x16)
static constexpr size_t WS_NEED   = OFF_A1T + 256ull*128*512*4;   // ~156 MiB

static constexpr size_t LDS_DYN = 131072;

struct KArgs {
  const float* in[22];
  float* out;
  uchar* ws;
};

__device__ __forceinline__ float fexp2(float x){ return __builtin_amdgcn_exp2f(x); }
__device__ __forceinline__ float frcp (float x){ return __builtin_amdgcn_rcpf(x); }
__device__ __forceinline__ float sigm (float x){ return frcp(1.f + fexp2(x * -1.44269504f)); }
__device__ __forceinline__ float tanh_(float x){ return 2.f*frcp(1.f + fexp2(x * -2.88539008f)) - 1.f; }
__device__ __forceinline__ unsigned short f2bf(float f){
  unsigned u = __float_as_uint(f);
  return (unsigned short)((u + 0x7fffu + ((u>>16)&1u)) >> 16);
}
__device__ __forceinline__ bf16x8 ldfrag(const uchar* p){ return *(const bf16x8*)p; }

// coherent (LLC-level) ops for cross-XCD state
__device__ __forceinline__ u64 ld_c64(const void* p){
  return __hip_atomic_load((const u64*)p, __ATOMIC_RELAXED, __HIP_MEMORY_SCOPE_AGENT);
}
__device__ __forceinline__ unsigned ld_c32(const void* p){
  return __hip_atomic_load((const unsigned*)p, __ATOMIC_RELAXED, __HIP_MEMORY_SCOPE_AGENT);
}
__device__ __forceinline__ float ld_c32f(const void* p){ return __uint_as_float(ld_c32(p)); }
__device__ __forceinline__ void st_c64(void* p, u64 v){
  __hip_atomic_store((u64*)p, v, __ATOMIC_RELAXED, __HIP_MEMORY_SCOPE_AGENT);
}
__device__ __forceinline__ void st_c32(void* p, unsigned v){
  __hip_atomic_store((unsigned*)p, v, __ATOMIC_RELAXED, __HIP_MEMORY_SCOPE_AGENT);
}
__device__ __forceinline__ bf16x8 ldfrag_c(const uchar* p){
  union { bf16x8 v; u64 u[2]; } r;
  r.u[0] = ld_c64(p); r.u[1] = ld_c64(p + 8);
  return r.v;
}

// hierarchical grid barrier; full=true adds agent fences (once, after setup)
__device__ __forceinline__ void gbar(uchar* bar, unsigned target, bool full) {
  __builtin_amdgcn_s_waitcnt(0);
  __syncthreads();
  if (threadIdx.x == 0) {
    if (full) __builtin_amdgcn_fence(__ATOMIC_RELEASE, "agent");
    unsigned g = blockIdx.x & 31;
    unsigned* cnt    = (unsigned*)(bar + g*128);
    unsigned* master = (unsigned*)(bar + 32*128);
    unsigned* flag   = (unsigned*)(bar + 33*128);
    bool setter = false;
    unsigned prev = __hip_atomic_fetch_add(cnt, 1u, __ATOMIC_RELAXED, __HIP_MEMORY_SCOPE_AGENT);
    if (prev == 8u*target - 1u) {
      unsigned pm = __hip_atomic_fetch_add(master, 1u, __ATOMIC_RELAXED, __HIP_MEMORY_SCOPE_AGENT);
      if (pm == 32u*target - 1u) {
        __hip_atomic_store(flag, target, __ATOMIC_RELAXED, __HIP_MEMORY_SCOPE_AGENT);
        setter = true;
      }
    }
    if (!setter) {
      while (__hip_atomic_load(flag, __ATOMIC_RELAXED, __HIP_MEMORY_SCOPE_AGENT) < target) {
        __builtin_amdgcn_s_sleep(2);
      }
    }
    if (full) __builtin_amdgcn_fence(__ATOMIC_ACQUIRE, "agent");
  }
  __syncthreads();
}

__global__ void __launch_bounds__(NTHR, 1) seq2seq(KArgs A) {
  extern __shared__ uchar ldsA[];
  const int bid = blockIdx.x, tid = threadIdx.x;
  const int lane = tid & 63, wv = tid >> 6;
  const int q = lane >> 4, cl = lane & 15;
  uchar* ws = A.ws;

  const float* src = A.in[0];
  const float* ew0 = A.in[1]; const float* eu0 = A.in[2];
  const float* ebi0= A.in[3]; const float* ebh0= A.in[4];
  const float* ew1 = A.in[5]; const float* eu1 = A.in[6];
  const float* ebi1= A.in[7]; const float* ebh1= A.in[8];
  const float* dw0 = A.in[9]; const float* du0 = A.in[10];
  const float* dbi0= A.in[11]; const float* dbh0= A.in[12];
  const float* dw1 = A.in[13]; const float* du1 = A.in[14];
  const float* dbi1= A.in[15]; const float* dbh1= A.in[16];
  const float* attW= A.in[17]; const float* attB= A.in[18];
  const float* vW  = A.in[19]; const float* fcW = A.in[20];
  const float* fcB = A.in[21];

  uchar* WX  = ws + OFF_WX;  uchar* W0H = ws + OFF_W0H;
  uchar* W1E = ws + OFF_W1E;
  uchar* W0D = ws + OFF_W0D; uchar* W1D = ws + OFF_W1D;
  uchar* WDP = ws + OFF_WDP; uchar* WEP = ws + OFF_WEP;
  float* BE0 = (float*)(ws + OFF_BE0); float* BE1 = (float*)(ws + OFF_BE1);
  float* BD0 = (float*)(ws + OFF_BD0); float* BD1 = (float*)(ws + OFF_BD1);
  uchar* XBF = ws + OFF_XBF;
  uchar* H0E[2] = { ws + OFF_H0E, ws + OFF_H0E + 256*512*2 };
  uchar* H1E[2] = { ws + OFF_H1E, ws + OFF_H1E + 256*512*2 };
  uchar* XD0[2] = { ws + OFF_XD0, ws + OFF_XD0 + 256*1056*2 };
  uchar* XD1[2] = { ws + OFF_XD1, ws + OFF_XD1 + 256*1024*2 };
  float* DP  = (float*)(ws + OFF_DP);
  float* C0g = (float*)(ws + OFF_C0);
  float* CS0 = (float*)(ws + OFF_CS0);
  float* CS1 = (float*)(ws + OFF_CS1);
  uchar* BAR = ws + OFF_BAR;
  uchar* ENCF8 = ws + OFF_ENCF8;
  unsigned* A1T = (unsigned*)(ws + OFF_A1T);

  __shared__ float smh[64][65];
  __shared__ float sm_d[512];
  __shared__ float sm_w[512];
  __shared__ float sm_ctx[512];
  __shared__ float sm_r[8];

  unsigned ep = 0;
  const int T = NBLK*NTHR; const int gt = bid*NTHR + tid;

  // =================== SETUP ===================
  {
    for (int i = gt; i < 2048*32; i += T) {
      int np = i >> 5, k = i & 31;
      int r = (np & 3)*512 + (np >> 2);
      ((unsigned short*)WX)[i] = f2bf(ew0[r*32 + k]);
    }
    for (int i = gt; i < 2048*512; i += T) {
      int np = i >> 9, k = i & 511;
      int r = (np & 3)*512 + (np >> 2);
      ((unsigned short*)W0H)[i] = f2bf(eu0[r*512 + k]);
    }
    for (int i = gt; i < 2048*1024; i += T) {
      int np = i >> 10, k = i & 1023;
      int r = (np & 3)*512 + (np >> 2);
      float v = (k < 512) ? ew1[r*512 + k] : eu1[r*512 + (k-512)];
      ((unsigned short*)W1E)[i] = f2bf(v);
    }
    for (int i = gt; i < 2048*1056; i += T) {
      int np = i / 1056, k = i - np*1056;
      int r = (np & 3)*512 + (np >> 2);
      float v;
      if (k < 512) v = dw0[r*513 + 1 + k];
      else if (k == 512) v = dw0[r*513];
      else if (k >= 520 && k < 1032) v = du0[r*512 + (k-520)];
      else v = 0.f;
      ((unsigned short*)W0D)[i] = f2bf(v);
    }
    for (int i = gt; i < 2048*1024; i += T) {
      int np = i >> 10, k = i & 1023;
      int r = (np & 3)*512 + (np >> 2);
      float v = (k < 512) ? dw1[r*512 + k] : du1[r*512 + (k-512)];
      ((unsigned short*)W1D)[i] = f2bf(v);
    }
    for (int i = gt; i < 640*512; i += T) {
      int j = i >> 9, k = i & 511;
      float v = (j < 512) ? attW[j*1024 + 512 + k] : ((j == 512) ? fcW[k] : 0.f);
      ((unsigned short*)WDP)[i] = f2bf(v);
    }
    for (int i = gt; i < 512*512; i += T) {
      int j = i >> 9, k = i & 511;
      ((unsigned short*)WEP)[i] = f2bf(attW[j*1024 + k]);
    }
    for (int i = gt; i < 2048; i += T) {
      int r = (i & 3)*512 + (i >> 2);
      BE0[i] = ebi0[r] + ebh0[r];
      BE1[i] = ebi1[r] + ebh1[r];
      BD0[i] = dbi0[r] + dbh0[r];
      BD1[i] = dbi1[r] + dbh1[r];
    }
    for (int i = gt; i < 512*256*32; i += T) {
      int t = i >> 13, rem = i & 8191;
      int b = rem >> 5, d = rem & 31;
      ((unsigned short*)XBF)[i] = f2bf(src[(b*512 + t)*32 + d]);
    }
    unsigned* Z = (unsigned*)(ws + OFF_H0E);
    for (int i = gt; i < 794624; i += T) Z[i] = 0u;   // H0E,H1E,XD0,XD1
    for (int i = gt; i < 256*512; i += T) C0g[i] = 0.f;
  }
  gbar(BAR, ++ep, true);   // the ONE full-fence barrier

  // =================== STAGE WEIGHT SLICE -> LDS (bank-swizzled) ===================
  // swizzled addr: row*ROWB + (off16*16 ^ ((row&7)*16))
  if (bid < 64) {                     // L0: 128 rows x 1024 B
    const int mm = bid >> 2;
    const uint4* s4 = (const uint4*)W0H;
    for (int i = tid; i < 8192; i += NTHR) {
      int r = i >> 6, c = i & 63;
      *(uint4*)(ldsA + (size_t)r*1024 + ((c*16) ^ ((r & 7)*16))) = s4[(size_t)(mm*128 + r)*64 + c];
    }
  } else if (bid < 192) {             // L1: 64 rows x 2048 B
    const int mm = (bid - 64) >> 2;
    const uint4* s4 = (const uint4*)W1E;
    for (int i = tid; i < 8192; i += NTHR) {
      int r = i >> 7, c = i & 127;
      *(uint4*)(ldsA + (size_t)r*2048 + ((c*16) ^ ((r & 7)*16))) = s4[(size_t)(mm*64 + r)*128 + c];
    }
  } else {                            // PROJ: 32 rows x 1024 B
    const int mm = (bid - 192) >> 2;
    const uint4* s4 = (const uint4*)WEP;
    for (int i = tid; i < 2048; i += NTHR) {
      int r = i >> 6, c = i & 63;
      *(uint4*)(ldsA + (size_t)r*1024 + ((c*16) ^ ((r & 7)*16))) = s4[(size_t)(mm*32 + r)*64 + c];
    }
  }
  __syncthreads();

  float cst[16];
#pragma unroll
  for (int i = 0; i < 16; ++i) cst[i] = 0.f;

  const int swz = (cl & 7) * 16;   // read-side XOR (row_local & 7 == cl & 7 since row = mi*16+cl)

  // =================== ENCODER: 514 pipelined phases ===================
  for (int p = 0; p <= 513; ++p) {
    if (bid < 64 && p < 512) {
      // ---- L0: 128 gate-rows x 64 cols, K=544 ----
      const int mm = bid >> 2, nn = bid & 3;
      const int colw = nn*64 + wv*16;
      const uchar* xrow = XBF + (size_t)p*16384;
      const uchar* h0rd = H0E[(p+1)&1];
      bf16x8 bring[8];
      auto ldB = [&](int kc)->bf16x8 {
        if (kc == 0) return ldfrag(xrow + (size_t)(colw + cl)*64 + q*16);
        return ldfrag_c(h0rd + (size_t)(colw + cl)*1024 + (size_t)(kc-1)*64 + q*16);
      };
#pragma unroll
      for (int i = 0; i < 8; ++i) bring[i] = ldB(i);
      f32x4 acc[8];
#pragma unroll
      for (int i = 0; i < 8; ++i) acc[i] = (f32x4){0.f,0.f,0.f,0.f};
#pragma unroll
      for (int kc = 0; kc < 17; ++kc) {
        bf16x8 b = bring[kc & 7];
        if (kc + 8 < 17) bring[kc & 7] = ldB(kc + 8);
#pragma unroll
        for (int mi = 0; mi < 8; ++mi) {
          bf16x8 a;
          if (kc == 0) a = ldfrag(WX + (size_t)(mm*128 + mi*16 + cl)*64 + q*16);
          else         a = ldfrag(ldsA + (size_t)(mi*16 + cl)*1024 + (((kc-1)*64 + q*16) ^ swz));
          acc[mi] = __builtin_amdgcn_mfma_f32_16x16x32_bf16(a, b, acc[mi], 0,0,0);
        }
      }
#pragma unroll
      for (int mi = 0; mi < 8; ++mi) {
        int row = mm*128 + mi*16 + 4*q;
        f32x4 b4 = *(const f32x4*)(BE0 + row);
        f32x4 g = acc[mi];
        float ii = sigm(g[0]+b4[0]), ff = sigm(g[1]+b4[1]);
        float gg = tanh_(g[2]+b4[2]), oo = sigm(g[3]+b4[3]);
        float cc = ff*cst[mi] + ii*gg;
        cst[mi] = cc;
        smh[wv*16 + cl][mi*4 + q] = oo * tanh_(cc);
      }
      if (p == 511) {
#pragma unroll
        for (int mi = 0; mi < 8; ++mi)
          st_c32(CS0 + (size_t)(colw + cl)*512 + mm*32 + mi*4 + q, __float_as_uint(cst[mi]));
      }
      __syncthreads();
      {
        int col = tid & 63, jq = tid >> 6;
        float v[8];
#pragma unroll
        for (int u = 0; u < 8; ++u) v[u] = smh[col][jq*8 + u];
        unsigned pk[4];
#pragma unroll
        for (int u = 0; u < 4; ++u) pk[u] = (unsigned)f2bf(v[2*u]) | ((unsigned)f2bf(v[2*u+1]) << 16);
        uchar* d = H0E[p&1] + ((size_t)(nn*64 + col)*512 + mm*32 + jq*8)*2;
        st_c64(d,     (u64)pk[0] | ((u64)pk[1] << 32));
        st_c64(d + 8, (u64)pk[2] | ((u64)pk[3] << 32));
      }
      __syncthreads();
    } else if (bid >= 64 && bid < 192 && p >= 1 && p <= 512) {
      // ---- L1: 64 gate-rows x 64 cols, K=1024 ----
      const int idx = bid - 64, mm = idx >> 2, nn = idx & 3;
      const int t = p - 1;
      const int colw = nn*64 + wv*16;
      const uchar* h0rd = H0E[(p+1)&1];
      const uchar* h1rd = H1E[(p+1)&1];
      bf16x8 bring[8];
      auto ldB = [&](int kc)->bf16x8 {
        const uchar* base = (kc < 16) ? h0rd : h1rd;
        int k0 = kc & 15;
        return ldfrag_c(base + (size_t)(colw + cl)*1024 + (size_t)k0*64 + q*16);
      };
#pragma unroll
      for (int i = 0; i < 8; ++i) bring[i] = ldB(i);
      f32x4 acc[4];
#pragma unroll
      for (int i = 0; i < 4; ++i) acc[i] = (f32x4){0.f,0.f,0.f,0.f};
#pragma unroll
      for (int kc = 0; kc < 32; ++kc) {
        bf16x8 b = bring[kc & 7];
        if (kc + 8 < 32) bring[kc & 7] = ldB(kc + 8);
#pragma unroll
        for (int mi = 0; mi < 4; ++mi) {
          bf16x8 a = ldfrag(ldsA + (size_t)(mi*16 + cl)*2048 + ((kc*64 + q*16) ^ swz));
          acc[mi] = __builtin_amdgcn_mfma_f32_16x16x32_bf16(a, b, acc[mi], 0,0,0);
        }
      }
#pragma unroll
      for (int mi = 0; mi < 4; ++mi) {
        int row = mm*64 + mi*16 + 4*q;
        f32x4 b4 = *(const f32x4*)(BE1 + row);
        f32x4 g = acc[mi];
        float ii = sigm(g[0]+b4[0]), ff = sigm(g[1]+b4[1]);
        float gg = tanh_(g[2]+b4[2]), oo = sigm(g[3]+b4[3]);
        float cc = ff*cst[mi] + ii*gg;
        cst[mi] = cc;
        smh[wv*16 + cl][mi*4 + q] = oo * tanh_(cc);
      }
      if (p == 512) {
#pragma unroll
        for (int mi = 0; mi < 4; ++mi)
          st_c32(CS1 + (size_t)(colw + cl)*512 + mm*16 + mi*4 + q, __float_as_uint(cst[mi]));
      }
      __syncthreads();
      {
        int col = tid & 63, jq = tid >> 6;
        float v[4];
#pragma unroll
        for (int u = 0; u < 4; ++u) v[u] = smh[col][jq*4 + u];
        unsigned p0 = (unsigned)f2bf(v[0]) | ((unsigned)f2bf(v[1]) << 16);
        unsigned p1 = (unsigned)f2bf(v[2]) | ((unsigned)f2bf(v[3]) << 16);
        uchar* d = H1E[p&1] + ((size_t)(nn*64 + col)*512 + mm*16 + jq*4)*2;
        st_c64(d, (u64)p0 | ((u64)p1 << 32));
        unsigned r8 = __builtin_amdgcn_cvt_pk_fp8_f32(v[0]*16.f, v[1]*16.f, 0, false);
        r8          = __builtin_amdgcn_cvt_pk_fp8_f32(v[2]*16.f, v[3]*16.f, r8, true);
        st_c32(ENCF8 + (size_t)(nn*64 + col)*262144 + (size_t)t*512 + mm*16 + jq*4, r8);
      }
      __syncthreads();
    } else if (bid >= 192 && p >= 2 && p <= 513) {
      // ---- PROJ: 32 E-dims x 64 cols + Taylor artifacts ----
      const int idx = bid - 192, mm = idx >> 2, nn = idx & 3;
      const int t = p - 2;
      const int colw = nn*64 + wv*16;
      const uchar* h1rd = H1E[(p+1)&1];
      bf16x8 bring[8];
      auto ldB = [&](int kc)->bf16x8 {
        return ldfrag_c(h1rd + (size_t)(colw + cl)*1024 + (size_t)kc*64 + q*16);
      };
#pragma unroll
      for (int i = 0; i < 8; ++i) bring[i] = ldB(i);
      f32x4 acc[2];
#pragma unroll
      for (int i = 0; i < 2; ++i) acc[i] = (f32x4){0.f,0.f,0.f,0.f};
#pragma unroll
      for (int kc = 0; kc < 16; ++kc) {
        bf16x8 b = bring[kc & 7];
        if (kc + 8 < 16) bring[kc & 7] = ldB(kc + 8);
#pragma unroll
        for (int mi = 0; mi < 2; ++mi) {
          bf16x8 a = ldfrag(ldsA + (size_t)(mi*16 + cl)*1024 + ((kc*64 + q*16) ^ swz));
          acc[mi] = __builtin_amdgcn_mfma_f32_16x16x32_bf16(a, b, acc[mi], 0,0,0);
        }
      }
      float part = 0.f;
      const int col = colw + cl;
#pragma unroll
      for (int mi = 0; mi < 2; ++mi) {
        int k0 = mm*32 + mi*16 + 4*q;
        f32x4 ab = *(const f32x4*)(attB + k0);
        f32x4 vv = *(const f32x4*)(vW + k0);
        f32x4 e = acc[mi];
        float t0 = tanh_(e[0]+ab[0]);
        float t1 = tanh_(e[1]+ab[1]);
        float t2 = tanh_(e[2]+ab[2]);
        float t3 = tanh_(e[3]+ab[3]);
        part += vv[0]*t0 + vv[1]*t1 + vv[2]*t2 + vv[3]*t3;
        float a0 = vv[0]*(1.f-t0*t0)*16.f, a1 = vv[1]*(1.f-t1*t1)*16.f;
        float a2 = vv[2]*(1.f-t2*t2)*16.f, a3 = vv[3]*(1.f-t3*t3)*16.f;
        unsigned u = __builtin_amdgcn_cvt_pk_fp8_f32(a0, a1, 0, false);
        u          = __builtin_amdgcn_cvt_pk_fp8_f32(a2, a3, u, true);
        st_c32(&A1T[((size_t)col*128 + (mm*8 + mi*4 + q))*512 + t], u);
      }
      part += __shfl_xor(part, 16);
      part += __shfl_xor(part, 32);
      if (q == 0) atomicAdd(&C0g[(size_t)col*512 + t], part);
    }
    gbar(BAR, ++ep, false);
  }

  // =================== TRANSITION ===================
  {
    uchar* x0 = XD0[0];
    uchar* x1 = XD1[0];
    const unsigned* h0f = (const unsigned*)H0E[1];  // h0(511)
    const unsigned* h1f = (const unsigned*)H1E[0];  // h1(511)
    for (int i = gt; i < 65536; i += T) {
      int b = i >> 8, j = i & 255;
      unsigned v0 = ld_c32(h0f + i);
      unsigned v1 = ld_c32(h1f + i);
      st_c32(x0 + (size_t)b*2112 + 1040 + j*4, v0);
      st_c32(x1 + (size_t)b*2048 + 1024 + j*4, v1);
    }
    for (int i = gt; i < 256; i += T) {
      unsigned v = (unsigned)f2bf(src[(i*512 + 511)*32 + 31]);
      st_c32(x0 + (size_t)i*2112 + 1024, v);
    }
  }
  gbar(BAR, ++ep, false);

  // decoder c-state reload (encoder partition differs)
  if (bid < 32) {
    const int m = bid >> 2, n = bid & 3;
#pragma unroll
    for (int mi = 0; mi < 4; ++mi)
#pragma unroll
      for (int ni = 0; ni < 4; ++ni)
        cst[mi*4+ni] = ld_c32f(CS0 + (size_t)(n*64 + ni*16 + cl)*512 + m*64 + wv*16 + mi*4 + q);
  } else if (bid < 64) {
    const int idx = bid - 32, m = idx >> 2, n = idx & 3;
#pragma unroll
    for (int mi = 0; mi < 4; ++mi)
#pragma unroll
      for (int ni = 0; ni < 4; ++ni)
        cst[mi*4+ni] = ld_c32f(CS1 + (size_t)(n*64 + ni*16 + cl)*512 + m*64 + wv*16 + mi*4 + q);
  }

  // decoder GEMM+cell (global A weights, coherent B)
  auto run_gemm_cell = [&](const uchar* W, int Kp2, int nkc, auto bfn,
                           const float* bias, int rowb_blk, int bb,
                           uchar* d1, int s1, uchar* d2, int s2) {
    f32x4 acc[16];
#pragma unroll
    for (int i = 0; i < 16; ++i) acc[i] = (f32x4){0.f,0.f,0.f,0.f};
    const int rowb_wave = rowb_blk + wv*64;
#pragma unroll 2
    for (int kc = 0; kc < nkc; ++kc) {
      bf16x8 bfr[4], afr[4];
#pragma unroll
      for (int ni = 0; ni < 4; ++ni) bfr[ni] = ldfrag_c(bfn(kc, bb + ni*16 + cl));
#pragma unroll
      for (int mi = 0; mi < 4; ++mi)
        afr[mi] = ldfrag(W + (size_t)(rowb_wave + mi*16 + cl)*Kp2 + (size_t)kc*64 + q*16);
#pragma unroll
      for (int mi = 0; mi < 4; ++mi)
#pragma unroll
        for (int ni = 0; ni < 4; ++ni)
          acc[mi*4+ni] = __builtin_amdgcn_mfma_f32_16x16x32_bf16(afr[mi], bfr[ni], acc[mi*4+ni], 0,0,0);
    }
#pragma unroll
    for (int mi = 0; mi < 4; ++mi) {
      int row = rowb_wave + mi*16 + 4*q;
      f32x4 bb4 = *(const f32x4*)(bias + row);
#pragma unroll
      for (int ni = 0; ni < 4; ++ni) {
        f32x4 g = acc[mi*4+ni];
        float ii = sigm(g[0] + bb4[0]);
        float ff = sigm(g[1] + bb4[1]);
        float gg = tanh_(g[2] + bb4[2]);
        float oo = sigm(g[3] + bb4[3]);
        float cc = ff*cst[mi*4+ni] + ii*gg;
        cst[mi*4+ni] = cc;
        smh[ni*16 + cl][wv*16 + mi*4 + q] = oo * tanh_(cc);
      }
    }
    __syncthreads();
    {
      int b = tid & 63, jq = tid >> 6;
      int jb = (rowb_blk >> 2) + jq*16;
      float v[16];
#pragma unroll
      for (int u = 0; u < 16; ++u) v[u] = smh[b][jq*16 + u];
      unsigned pk[8];
#pragma unroll
      for (int u = 0; u < 8; ++u) pk[u] = (unsigned)f2bf(v[2*u]) | ((unsigned)f2bf(v[2*u+1]) << 16);
      u64 q0 = (u64)pk[0] | ((u64)pk[1] << 32);
      u64 q1 = (u64)pk[2] | ((u64)pk[3] << 32);
      u64 q2 = (u64)pk[4] | ((u64)pk[5] << 32);
      u64 q3 = (u64)pk[6] | ((u64)pk[7] << 32);
      uchar* p1 = d1 + ((size_t)(bb+b)*s1 + jb)*2;
      st_c64(p1,      q0); st_c64(p1 + 8,  q1);
      st_c64(p1 + 16, q2); st_c64(p1 + 24, q3);
      if (d2) {
        uchar* p2 = d2 + ((size_t)(bb+b)*s2 + jb)*2;
        st_c64(p2,      q0); st_c64(p2 + 8,  q1);
        st_c64(p2 + 16, q2); st_c64(p2 + 24, q3);
      }
    }
    __syncthreads();
  };

  // =================== DECODER ===================
  for (int t = 0; t <= 24; ++t) {
    // ---- P3b: dp = [W_dec; fc_W] @ h1(t-1) ----
    if (bid < 20) {
      const int m = bid >> 2, n = bid & 3;
      const uchar* xb = XD1[t&1];
      f32x4 acc[8];
#pragma unroll
      for (int i = 0; i < 8; ++i) acc[i] = (f32x4){0.f,0.f,0.f,0.f};
      const int rb = m*128 + wv*32;
#pragma unroll 2
      for (int kc = 0; kc < 16; ++kc) {
        bf16x8 bfr[4], afr[2];
#pragma unroll
        for (int ni = 0; ni < 4; ++ni)
          bfr[ni] = ldfrag_c(xb + (size_t)(n*64 + ni*16 + cl)*2048 + 1024 + (size_t)kc*64 + q*16);
#pragma unroll
        for (int mi = 0; mi < 2; ++mi)
          afr[mi] = ldfrag(WDP + (size_t)(rb + mi*16 + cl)*1024 + (size_t)kc*64 + q*16);
#pragma unroll
        for (int mi = 0; mi < 2; ++mi)
#pragma unroll
          for (int ni = 0; ni < 4; ++ni)
            acc[mi*4+ni] = __builtin_amdgcn_mfma_f32_16x16x32_bf16(afr[mi], bfr[ni], acc[mi*4+ni], 0,0,0);
      }
#pragma unroll
      for (int mi = 0; mi < 2; ++mi) {
        int j0 = rb + mi*16 + 4*q;
        if (j0 < 520) {
#pragma unroll
          for (int ni = 0; ni < 4; ++ni) {
            int bcol = n*64 + ni*16 + cl;
            union { f32x4 v; u64 u[2]; } cv; cv.v = acc[mi*4+ni];
            float* dst = DP + (size_t)bcol*520 + j0;
            st_c64(dst,     cv.u[0]);
            st_c64(dst + 2, cv.u[1]);
          }
        }
      }
    }
    gbar(BAR, ++ep, false);

    // ---- P1: pred/dec_in + Taylor scores + softmax + context ----
    {
      const int b = bid;
      float* dpb = DP + (size_t)b*520;
      uchar* xd0c = XD0[t&1];
      if (tid == 0 && t >= 1) {
        float pred = ld_c32f(dpb + 512) + fcB[0];
        A.out[b*24 + (t-1)] = pred;
        if (t < 24) {
          float hist = src[(b*512 + 511)*32 + 17];
          float dec_in = 0.8f*pred + 0.2f*hist;
          st_c32(xd0c + (size_t)b*2112 + 1024, (unsigned)f2bf(dec_in));
        }
      }
      if (t < 24) {
        sm_d[tid]       = ld_c32f(dpb + tid)       * 0.0625f;
        sm_d[tid + 256] = ld_c32f(dpb + tid + 256) * 0.0625f;
        __syncthreads();
        const unsigned* a1 = A1T + (size_t)b*128*512;
        float s0 = ld_c32f(C0g + (size_t)b*512 + tid);
        float s1 = ld_c32f(C0g + (size_t)b*512 + tid + 256);
        for (int kq = 0; kq < 128; ++kq) {
          unsigned u0 = ld_c32(a1 + kq*512 + tid);
          unsigned u1 = ld_c32(a1 + kq*512 + tid + 256);
          float d0 = sm_d[kq*4 + 0];
          float d1 = sm_d[kq*4 + 1];
          float d2 = sm_d[kq*4 + 2];
          float d3 = sm_d[kq*4 + 3];
          s0 += __builtin_amdgcn_cvt_f32_fp8(u0, 0) * d0
              + __builtin_amdgcn_cvt_f32_fp8(u0, 1) * d1
              + __builtin_amdgcn_cvt_f32_fp8(u0, 2) * d2
              + __builtin_amdgcn_cvt_f32_fp8(u0, 3) * d3;
          s1 += __builtin_amdgcn_cvt_f32_fp8(u1, 0) * d0
              + __builtin_amdgcn_cvt_f32_fp8(u1, 1) * d1
              + __builtin_amdgcn_cvt_f32_fp8(u1, 2) * d2
              + __builtin_amdgcn_cvt_f32_fp8(u1, 3) * d3;
        }
        float mx = fmaxf(s0, s1);
#pragma unroll
        for (int o = 1; o < 64; o <<= 1) mx = fmaxf(mx, __shfl_xor(mx, o));
        if (lane == 0) sm_r[wv] = mx;
        __syncthreads();
        mx = fmaxf(fmaxf(sm_r[0], sm_r[1]), fmaxf(sm_r[2], sm_r[3]));
        float e0 = fexp2((s0 - mx)*1.44269504f);
        float e1 = fexp2((s1 - mx)*1.44269504f);
        float sum = e0 + e1;
#pragma unroll
        for (int o = 1; o < 64; o <<= 1) sum += __shfl_xor(sum, o);
        if (lane == 0) sm_r[4 + wv] = sum;
        __syncthreads();
        sum = sm_r[4] + sm_r[5] + sm_r[6] + sm_r[7];
        float inv = frcp(sum) * 0.0625f;
        sm_w[tid] = e0*inv; sm_w[tid + 256] = e1*inv;
        sm_ctx[tid] = 0.f;  sm_ctx[tid + 256] = 0.f;
        __syncthreads();
        {
          int hp = (tid & 127)*4, sh = tid >> 7;
          const uchar* e8 = ENCF8 + (size_t)b*262144 + hp;
          float a0=0.f, a1f=0.f, a2=0.f, a3=0.f;
          for (int i = 0; i < 256; ++i) {
            int s = sh*256 + i;
            unsigned u = ld_c32(e8 + (size_t)s*512);
            float w = sm_w[s];
            a0  += w*__builtin_amdgcn_cvt_f32_fp8(u, 0);
            a1f += w*__builtin_amdgcn_cvt_f32_fp8(u, 1);
            a2  += w*__builtin_amdgcn_cvt_f32_fp8(u, 2);
            a3  += w*__builtin_amdgcn_cvt_f32_fp8(u, 3);
          }
          atomicAdd(&sm_ctx[hp+0], a0);
          atomicAdd(&sm_ctx[hp+1], a1f);
          atomicAdd(&sm_ctx[hp+2], a2);
          atomicAdd(&sm_ctx[hp+3], a3);
        }
        __syncthreads();
        unsigned pk0 = (unsigned)f2bf(sm_ctx[2*tid]) | ((unsigned)f2bf(sm_ctx[2*tid+1]) << 16);
        st_c32(xd0c + (size_t)b*2112 + tid*4, pk0);
      }
    }
    gbar(BAR, ++ep, false);

    // ---- P2: decoder L0 ----
    if (t < 24 && bid < 32) {
      const int m = bid >> 2, n = bid & 3;
      const uchar* xb = XD0[t&1];
      auto bfn = [&](int kc, int brow)->const uchar* {
        return xb + (size_t)brow*2112 + (size_t)kc*64 + q*16;
      };
      run_gemm_cell(W0D, 1056*2, 33, bfn, BD0, m*256, n*64,
                    XD1[t&1], 1024,
                    XD0[(t+1)&1] + 520*2, 1056);
    }
    gbar(BAR, ++ep, false);

    // ---- P3: decoder L1 ----
    if (t < 24 && bid >= 32 && bid < 64) {
      const int idx = bid - 32, m = idx >> 2, n = idx & 3;
      const uchar* xb = XD1[t&1];
      auto bfn = [&](int kc, int brow)->const uchar* {
        return xb + (size_t)brow*2048 + (size_t)kc*64 + q*16;
      };
      run_gemm_cell(W1D, 1024*2, 32, bfn, BD1, m*256, n*64,
                    XD1[(t+1)&1] + 512*2, 1024,
                    nullptr, 0);
    }
    gbar(BAR, ++ep, false);
  }
}

extern "C" void kernel_launch(void* const* d_in, const int* in_sizes, int n_in,
                              void* d_out, int out_size, void* d_ws, size_t ws_size,
                              hipStream_t stream) {
  (void)in_sizes; (void)n_in; (void)out_size;
  if (ws_size < WS_NEED) {
    fprintf(stderr, "seq2seq: ws too small: have %zu need %zu — NOT launching\n",
            ws_size, (size_t)WS_NEED);
    return;
  }
  (void)hipFuncSetAttribute((const void*)seq2seq,
                            hipFuncAttributeMaxDynamicSharedMemorySize, (int)LDS_DYN);
  (void)hipMemsetAsync((char*)d_ws + OFF_BAR, 0, BAR_SZ, stream);
  KArgs a;
  for (int i = 0; i < 22; ++i) a.in[i] = (const float*)d_in[i];
  a.out = (float*)d_out;
  a.ws  = (uchar*)d_ws;
  void* args[] = { (void*)&a };
  hipError_t e = hipLaunchCooperativeKernel((const void*)seq2seq, dim3(NBLK), dim3(NTHR),
                                            args, LDS_DYN, stream);
  if (e != hipSuccess) {
    fprintf(stderr, "seq2seq: coop launch failed (%d: %s), falling back to plain launch\n",
            (int)e, hipGetErrorString(e));
    seq2seq<<<dim3(NBLK), dim3(NTHR), LDS_DYN, stream>>>(a);
  }
}